// Round 8
// baseline (242.391 us; speedup 1.0000x reference)
//
#include <hip/hip_runtime.h>
#include <stdint.h>

#define AS1 __attribute__((address_space(1)))
#define AS3 __attribute__((address_space(3)))

typedef __bf16 bf16x8 __attribute__((ext_vector_type(8)));
typedef float f32x4 __attribute__((ext_vector_type(4)));
typedef unsigned int u32x4 __attribute__((ext_vector_type(4)));

constexpr int NB = 8;     // batches
constexpr int N  = 2048;  // nodes
constexpr int F  = 128;   // features (in == out)

__device__ __forceinline__ unsigned short bf16r(float f) {
    unsigned u = __float_as_uint(f);
    return (unsigned short)((u + 0x7FFFu + ((u >> 16) & 1u)) >> 16);
}
__device__ __forceinline__ float bf2f(unsigned short s) {
    return __uint_as_float(((unsigned)s) << 16);
}

// ---------------------------------------------------------------------------
// Wb2 element layout (MFMA-B-operand native, linear in k-chunks):
//   byte(b, n, o) = b*N*F*2 + (n>>3)*2048 + o*16 + (n&7)*2
// BK=64 chunk c = contiguous 16384 B at b*N*F*2 + c*16384.
//
// maskG bit layout (written by compress, read by k3):
//   per global row r (= b*2048+i), 256 B: 16 t-slots of 16 B; t covers
//   j in [t*128, t*128+128). Slot = {m0.lo, m0.hi, m1.lo, m1.hi} where
//   m0 bit l = (adj[r][t*128+2l]   != 0)   (even j)
//   m1 bit l = (adj[r][t*128+2l+1] != 0)   (odd j)
// ---------------------------------------------------------------------------

// K01: fused k1 (blocks 0..255, unchanged math) + adj->bitmask compress
// (blocks 256..2303; 8 rows/block; __ballot packing; pure HBM stream).
__global__ __launch_bounds__(256) void k01_wh(const float* __restrict__ h,
                                              const float* __restrict__ adj,
                                              const float* __restrict__ W,
                                              const float* __restrict__ a,
                                              unsigned short* __restrict__ Wb2,
                                              unsigned short* __restrict__ p16,
                                              unsigned char* __restrict__ maskG) {
    const int tid  = threadIdx.x;
    const int lane = tid & 63, wid = tid >> 6;

    if (blockIdx.x >= 256) {
        // ---- compress: adj (134 MB f32) -> maskG (4 MB bits) ----
        const int cid = blockIdx.x - 256;           // 0..2047
#pragma unroll
        for (int rr = 0; rr < 2; ++rr) {
            const int row = cid * 8 + wid * 2 + rr; // global row 0..16383
            const float2* src = (const float2*)(adj + (size_t)row * 2048) + lane;
            u32x4* dst = (u32x4*)(maskG + (size_t)row * 256);
#pragma unroll 4
            for (int t = 0; t < 16; ++t) {
                float2 v = src[t * 64];
                unsigned long long m0 = __ballot(v.x > 0.5f);
                unsigned long long m1 = __ballot(v.y > 0.5f);
                if (lane == 0) {
                    u32x4 w = { (unsigned)m0, (unsigned)(m0 >> 32),
                                (unsigned)m1, (unsigned)(m1 >> 32) };
                    dst[t] = w;
                }
            }
        }
        return;
    }

    // ---- k1 (unchanged, proven): Wh = h @ W^T; e = Wh @ a2; p = exp(e);
    //      p16 = bf16(p); Wb2 = bf16(bf2f(p16) * Wh) ----
    __shared__ float epart[2][64];

    const int quad = lane >> 4, l15 = lane & 15;
    const int wm = wid >> 1, wn = wid & 1;
    const int m0 = blockIdx.x * 64;
    const int batch = m0 >> 11;
    const int nbase = m0 & 2047;

    f32x4 acc[2][4] = {};

#pragma unroll
    for (int kk = 0; kk < 4; ++kk) {
        const int k = kk * 32 + quad * 8;
        bf16x8 afr[2], bfr[4];
#pragma unroll
        for (int rt = 0; rt < 2; ++rt) {
            const float* src = h + (size_t)(m0 + wm * 32 + rt * 16 + l15) * F + k;
            float4 x0 = *(const float4*)src;
            float4 x1 = *(const float4*)(src + 4);
            afr[rt][0] = (__bf16)x0.x; afr[rt][1] = (__bf16)x0.y;
            afr[rt][2] = (__bf16)x0.z; afr[rt][3] = (__bf16)x0.w;
            afr[rt][4] = (__bf16)x1.x; afr[rt][5] = (__bf16)x1.y;
            afr[rt][6] = (__bf16)x1.z; afr[rt][7] = (__bf16)x1.w;
        }
#pragma unroll
        for (int ct = 0; ct < 4; ++ct) {
            const int o = wn * 64 + ct * 16 + l15;
            const float* src = W + (size_t)o * F + k;
            float4 x0 = *(const float4*)src;
            float4 x1 = *(const float4*)(src + 4);
            bfr[ct][0] = (__bf16)x0.x; bfr[ct][1] = (__bf16)x0.y;
            bfr[ct][2] = (__bf16)x0.z; bfr[ct][3] = (__bf16)x0.w;
            bfr[ct][4] = (__bf16)x1.x; bfr[ct][5] = (__bf16)x1.y;
            bfr[ct][6] = (__bf16)x1.z; bfr[ct][7] = (__bf16)x1.w;
        }
#pragma unroll
        for (int rt = 0; rt < 2; ++rt)
#pragma unroll
            for (int ct = 0; ct < 4; ++ct)
                acc[rt][ct] = __builtin_amdgcn_mfma_f32_16x16x32_bf16(
                    afr[rt], bfr[ct], acc[rt][ct], 0, 0, 0);
    }

    float a2v[4];
#pragma unroll
    for (int ct = 0; ct < 4; ++ct) a2v[ct] = a[F + wn * 64 + ct * 16 + l15];

    float ep[2][4];
#pragma unroll
    for (int rt = 0; rt < 2; ++rt)
#pragma unroll
        for (int g = 0; g < 4; ++g) {
            float s = 0.f;
#pragma unroll
            for (int ct = 0; ct < 4; ++ct) s += acc[rt][ct][g] * a2v[ct];
            ep[rt][g] = s;
        }
#pragma unroll
    for (int m = 1; m < 16; m <<= 1)
#pragma unroll
        for (int rt = 0; rt < 2; ++rt)
#pragma unroll
            for (int g = 0; g < 4; ++g)
                ep[rt][g] += __shfl_xor(ep[rt][g], m);

    if (l15 == 0)
#pragma unroll
        for (int rt = 0; rt < 2; ++rt)
#pragma unroll
            for (int g = 0; g < 4; ++g)
                epart[wn][wm * 32 + rt * 16 + quad * 4 + g] = ep[rt][g];
    __syncthreads();

#pragma unroll
    for (int rt = 0; rt < 2; ++rt)
#pragma unroll
        for (int ct = 0; ct < 4; ++ct) {
            const int o  = wn * 64 + ct * 16 + l15;
            const int r0 = wm * 32 + rt * 16 + quad * 4;
            const int n0 = nbase + r0;
            ushort4 v;
#pragma unroll
            for (int g = 0; g < 4; ++g) {
                const float e  = epart[0][r0 + g] + epart[1][r0 + g];
                const float pf = bf2f(bf16r(expf(e)));
                (&v.x)[g] = bf16r(pf * acc[rt][ct][g]);
            }
            size_t off = (size_t)batch * N * F + (size_t)(n0 >> 3) * 1024 + o * 8 + (n0 & 7);
            *(ushort4*)&Wb2[off] = v;
        }

    if (tid < 64) {
        const float e = epart[0][tid] + epart[1][tid];
        p16[batch * N + nbase + tid] = bf16r(expf(e));
    }
}

// K3 v7: bitmask A (zero adj traffic in-loop) + v6's B ring pipeline.
//   out[b][i][o] = (sum_j adj[b][i][j]*Wb2[j][o]) / (sum_j adj[b][i][j]*p[j])
// A-fragment synthesized from bits: exact 0.0/1.0 bf16 -> numerics identical.
// Mask tile (64 rows x 256 B = 16 KB) loaded ONCE into LDS (slot-XOR swizzle
// (t+row)&15 -> <=2-way banks = free). B = v6 structure: BK=64, 32 chunks,
// ring-3 shared buffers, 2 gll/wave/chunk, counted vmcnt(4) BEFORE raw
// s_barrier (never 0 mid-loop), second barrier before restage. Grid 256,
// blk&7 = batch XCD pin (Wb2 512 KB + p16 4 KB L2-resident). 512 thr = 8
// waves 2Mx4N. LDS = 3x16 (B) + 4 (P) + 16 (M) = 68 KB. k3 HBM ~= 12 MB.
__global__ __launch_bounds__(512, 2) void k3_fused(const unsigned char* __restrict__ maskG,
                                                   const unsigned short* __restrict__ Wb2,
                                                   const unsigned short* __restrict__ p16,
                                                   float* __restrict__ out) {
    __shared__ __align__(16) char Bsm_[3][16384];   // 64 k x 128 o bf16, linear image
    __shared__ __align__(16) char Psm_[4096];       // 2048 x bf16
    __shared__ __align__(16) char Msm_[16384];      // 64 rows x 256 B mask, slot-swizzled

    const int tid  = threadIdx.x;
    const int lane = tid & 63, wid = tid >> 6;      // 8 waves
    const int quad = lane >> 4, l15 = lane & 15;
    const int wr = wid >> 2, wc = wid & 3;          // row-half / col-quarter
    const int b  = blockIdx.x & 7;
    const int it = blockIdx.x >> 3;                 // 0..31
    const int i0 = it * 64;

    // ---- prologue ----
    // mask: 16 KB, 512 threads x 32 B, reg-staged then swizzle-written.
    const int mr = tid >> 3;                        // row 0..63
    const int tp = (tid & 7) * 2;                   // t-slot pair
    const u32x4* mg = (const u32x4*)(maskG + ((size_t)(b * 2048 + i0 + mr)) * 256
                                     + (size_t)tp * 16);
    u32x4 mv0 = mg[0];
    u32x4 mv1 = mg[1];
    // p16 (4 KB, wave 0)
    if (wid == 0) {
        const char* pSrc = (const char*)p16 + (size_t)b * N * 2 + lane * 16;
#pragma unroll
        for (int s = 0; s < 4; ++s)
            __builtin_amdgcn_global_load_lds((const AS1 void*)(pSrc + s * 1024),
                (AS3 void*)(&Psm_[s * 1024]), 16, 0, 0);
    }
    *(u32x4*)&Msm_[mr * 256 + (((tp + 0) + mr) & 15) * 16] = mv0;
    *(u32x4*)&Msm_[mr * 256 + (((tp + 1) + mr) & 15) * 16] = mv1;
    __syncthreads();   // one-time full drain: mask writes + p landed

    // B stage source: linear 16 KB chunk image, wave's 2 KB slice.
    const char* bSrc = (const char*)Wb2 + (size_t)b * (N * F * 2)
                     + wid * 2048 + lane * 16;

#define K3_STAGE(BI, C)                                                            \
    do {                                                                           \
        __builtin_amdgcn_global_load_lds(                                          \
            (const AS1 void*)(bSrc + (size_t)(C) * 16384 + 0 * 1024),              \
            (AS3 void*)(&Bsm_[BI][wid * 2048 + 0 * 1024]), 16, 0, 0);              \
        __builtin_amdgcn_global_load_lds(                                          \
            (const AS1 void*)(bSrc + (size_t)(C) * 16384 + 1 * 1024),              \
            (AS3 void*)(&Bsm_[BI][wid * 2048 + 1 * 1024]), 16, 0, 0);              \
    } while (0)

    f32x4 acc[2][2] = {};
    f32x4 dacc[2] = {};

    K3_STAGE(0, 0);
    K3_STAGE(1, 1);
    K3_STAGE(2, 2);

#define K3_CHUNK(C, BI, WAITSTR, DOSTAGE)                                          \
    {                                                                              \
        asm volatile(WAITSTR ::: "memory");                                        \
        __builtin_amdgcn_s_barrier();                                              \
        __builtin_amdgcn_sched_barrier(0);                                         \
        const char* bB = &Bsm_[BI][0];                                             \
        /* per-rt mask words for this chunk (one b128 each, reused by both ks) */  \
        unsigned uE[2], uO[2];                                                     \
        _Pragma("unroll")                                                          \
        for (int rt = 0; rt < 2; ++rt) {                                           \
            const int row = wr * 32 + rt * 16 + l15;                               \
            u32x4 q = *(const u32x4*)&Msm_[row * 256                               \
                          + (((((C) >> 1)) + row) & 15) * 16];                     \
            uE[rt] = ((C) & 1) ? q.y : q.x;                                        \
            uO[rt] = ((C) & 1) ? q.w : q.z;                                        \
        }                                                                          \
        _Pragma("unroll")                                                          \
        for (int ks = 0; ks < 2; ++ks) {                                           \
            bf16x8 pv = *(const bf16x8*)(&Psm_[(C) * 128 + ks * 64 + quad * 16]);  \
            bf16x8 af[2];                                                          \
            _Pragma("unroll")                                                      \
            for (int rt = 0; rt < 2; ++rt) {                                       \
                const int base = ks * 16 + quad * 4;                               \
                u32x4 aw;                                                          \
                _Pragma("unroll")                                                  \
                for (int i = 0; i < 4; ++i) {                                      \
                    const int bi = base + i;                                       \
                    aw[i] = (((uE[rt] >> bi) & 1u) ? 0x00003F80u : 0u)             \
                          | (((uO[rt] >> bi) & 1u) ? 0x3F800000u : 0u);            \
                }                                                                  \
                af[rt] = __builtin_bit_cast(bf16x8, aw);                           \
            }                                                                      \
            _Pragma("unroll")                                                      \
            for (int ct = 0; ct < 2; ++ct) {                                       \
                bf16x8 bf = *(const bf16x8*)(bB + (ks * 4 + quad) * 2048           \
                                + (wc * 32 + ct * 16) * 16 + l15 * 16);            \
                acc[0][ct] = __builtin_amdgcn_mfma_f32_16x16x32_bf16(              \
                    af[0], bf, acc[0][ct], 0, 0, 0);                               \
                acc[1][ct] = __builtin_amdgcn_mfma_f32_16x16x32_bf16(              \
                    af[1], bf, acc[1][ct], 0, 0, 0);                               \
            }                                                                      \
            dacc[0] = __builtin_amdgcn_mfma_f32_16x16x32_bf16(                     \
                af[0], pv, dacc[0], 0, 0, 0);                                      \
            dacc[1] = __builtin_amdgcn_mfma_f32_16x16x32_bf16(                     \
                af[1], pv, dacc[1], 0, 0, 0);                                      \
        }                                                                          \
        if (DOSTAGE) {                                                             \
            __builtin_amdgcn_s_barrier();                                          \
            __builtin_amdgcn_sched_barrier(0);                                     \
            K3_STAGE(BI, (C) + 3);                                                 \
        }                                                                          \
    }

    // Main: chunk c restages c+3 (c <= 28; last staged = 31). Ring index is
    // compile-time; steady wait = vmcnt(4) (2 newer chunks x 2 own loads).
    for (int c3 = 0; c3 < 27; c3 += 3) {
        K3_CHUNK(c3 + 0, 0, "s_waitcnt vmcnt(4)", 1)
        K3_CHUNK(c3 + 1, 1, "s_waitcnt vmcnt(4)", 1)
        K3_CHUNK(c3 + 2, 2, "s_waitcnt vmcnt(4)", 1)
    }
    K3_CHUNK(27, 0, "s_waitcnt vmcnt(4)", 1)   // stages 30
    K3_CHUNK(28, 1, "s_waitcnt vmcnt(4)", 1)   // stages 31
    K3_CHUNK(29, 2, "s_waitcnt vmcnt(4)", 0)
    K3_CHUNK(30, 0, "s_waitcnt vmcnt(2)", 0)
    K3_CHUNK(31, 1, "s_waitcnt vmcnt(0)", 0)

#undef K3_CHUNK
#undef K3_STAGE

    // Epilogue: divide by per-row denominator (C/D row = quad*4+g holds the
    // matching dacc[rt][g] in every lane) and store final f32.
#pragma unroll
    for (int rt = 0; rt < 2; ++rt)
#pragma unroll
        for (int g = 0; g < 4; ++g) {
            const float inv = 1.0f / dacc[rt][g];
            float* orow = out + ((size_t)b * N + i0 + wr * 32 + rt * 16
                                 + quad * 4 + g) * F + wc * 32 + l15;
            orow[0]  = acc[rt][0][g] * inv;
            orow[16] = acc[rt][1][g] * inv;
        }
}

// ---------------------------------------------------------------------------
extern "C" void kernel_launch(void* const* d_in, const int* in_sizes, int n_in,
                              void* d_out, int out_size, void* d_ws, size_t ws_size,
                              hipStream_t stream) {
    const float* h   = (const float*)d_in[0];
    const float* adj = (const float*)d_in[1];
    const float* W   = (const float*)d_in[2];
    const float* a   = (const float*)d_in[3];
    float* out = (float*)d_out;

    unsigned short* Wb2  = (unsigned short*)d_ws;                        // 4 MB
    unsigned short* p16  = (unsigned short*)((char*)d_ws + (4u << 20));  // 32 KB
    unsigned char*  maskG = (unsigned char*)((char*)d_ws + (8u << 20));  // 4 MB

    k01_wh<<<256 + 2048, 256, 0, stream>>>(h, adj, W, a, Wb2, p16, maskG);
    k3_fused<<<NB * 32, 512, 0, stream>>>(maskG, Wb2, p16, out);
}

// Round 9
// 240.567 us; speedup vs baseline: 1.0076x; 1.0076x over previous
//
#include <hip/hip_runtime.h>
#include <stdint.h>

#define AS1 __attribute__((address_space(1)))
#define AS3 __attribute__((address_space(3)))

typedef __bf16 bf16x8 __attribute__((ext_vector_type(8)));
typedef float f32x4 __attribute__((ext_vector_type(4)));
typedef unsigned int u32x4 __attribute__((ext_vector_type(4)));

constexpr int NB = 8;     // batches
constexpr int N  = 2048;  // nodes
constexpr int F  = 128;   // features (in == out)

__device__ __forceinline__ unsigned short bf16r(float f) {
    unsigned u = __float_as_uint(f);
    return (unsigned short)((u + 0x7FFFu + ((u >> 16) & 1u)) >> 16);
}
__device__ __forceinline__ float bf2f(unsigned short s) {
    return __uint_as_float(((unsigned)s) << 16);
}

// ---------------------------------------------------------------------------
// Wb2 element layout (MFMA-B-operand native, linear in k-chunks):
//   byte(b, n, o) = b*N*F*2 + (n>>3)*2048 + o*16 + (n&7)*2
// K=32 chunk at j0 = contiguous 8192 B at b*N*F*2 + j0*256.
//
// maskG bit layout (written by compress, read by k3):
//   per global row r (= b*2048+i), 256 B: 16 t-slots of 16 B; t covers
//   j in [t*128, t*128+128). Slot = {m0.lo, m0.hi, m1.lo, m1.hi} where
//   m0 bit l = (adj[r][t*128+2l]   != 0)   (even j)
//   m1 bit l = (adj[r][t*128+2l+1] != 0)   (odd j)
// ---------------------------------------------------------------------------

// K01: fused k1 (blocks 0..255, unchanged math) + adj->bitmask compress
// (blocks 256..2303; 8 rows/block; __ballot packing; pure HBM stream).
// [byte-identical to R8's proven version]
__global__ __launch_bounds__(256) void k01_wh(const float* __restrict__ h,
                                              const float* __restrict__ adj,
                                              const float* __restrict__ W,
                                              const float* __restrict__ a,
                                              unsigned short* __restrict__ Wb2,
                                              unsigned short* __restrict__ p16,
                                              unsigned char* __restrict__ maskG) {
    const int tid  = threadIdx.x;
    const int lane = tid & 63, wid = tid >> 6;

    if (blockIdx.x >= 256) {
        // ---- compress: adj (134 MB f32) -> maskG (4 MB bits) ----
        const int cid = blockIdx.x - 256;           // 0..2047
#pragma unroll
        for (int rr = 0; rr < 2; ++rr) {
            const int row = cid * 8 + wid * 2 + rr; // global row 0..16383
            const float2* src = (const float2*)(adj + (size_t)row * 2048) + lane;
            u32x4* dst = (u32x4*)(maskG + (size_t)row * 256);
#pragma unroll 4
            for (int t = 0; t < 16; ++t) {
                float2 v = src[t * 64];
                unsigned long long m0 = __ballot(v.x > 0.5f);
                unsigned long long m1 = __ballot(v.y > 0.5f);
                if (lane == 0) {
                    u32x4 w = { (unsigned)m0, (unsigned)(m0 >> 32),
                                (unsigned)m1, (unsigned)(m1 >> 32) };
                    dst[t] = w;
                }
            }
        }
        return;
    }

    // ---- k1 (unchanged, proven): Wh = h @ W^T; e = Wh @ a2; p = exp(e);
    //      p16 = bf16(p); Wb2 = bf16(bf2f(p16) * Wh) ----
    __shared__ float epart[2][64];

    const int quad = lane >> 4, l15 = lane & 15;
    const int wm = wid >> 1, wn = wid & 1;
    const int m0 = blockIdx.x * 64;
    const int batch = m0 >> 11;
    const int nbase = m0 & 2047;

    f32x4 acc[2][4] = {};

#pragma unroll
    for (int kk = 0; kk < 4; ++kk) {
        const int k = kk * 32 + quad * 8;
        bf16x8 afr[2], bfr[4];
#pragma unroll
        for (int rt = 0; rt < 2; ++rt) {
            const float* src = h + (size_t)(m0 + wm * 32 + rt * 16 + l15) * F + k;
            float4 x0 = *(const float4*)src;
            float4 x1 = *(const float4*)(src + 4);
            afr[rt][0] = (__bf16)x0.x; afr[rt][1] = (__bf16)x0.y;
            afr[rt][2] = (__bf16)x0.z; afr[rt][3] = (__bf16)x0.w;
            afr[rt][4] = (__bf16)x1.x; afr[rt][5] = (__bf16)x1.y;
            afr[rt][6] = (__bf16)x1.z; afr[rt][7] = (__bf16)x1.w;
        }
#pragma unroll
        for (int ct = 0; ct < 4; ++ct) {
            const int o = wn * 64 + ct * 16 + l15;
            const float* src = W + (size_t)o * F + k;
            float4 x0 = *(const float4*)src;
            float4 x1 = *(const float4*)(src + 4);
            bfr[ct][0] = (__bf16)x0.x; bfr[ct][1] = (__bf16)x0.y;
            bfr[ct][2] = (__bf16)x0.z; bfr[ct][3] = (__bf16)x0.w;
            bfr[ct][4] = (__bf16)x1.x; bfr[ct][5] = (__bf16)x1.y;
            bfr[ct][6] = (__bf16)x1.z; bfr[ct][7] = (__bf16)x1.w;
        }
#pragma unroll
        for (int rt = 0; rt < 2; ++rt)
#pragma unroll
            for (int ct = 0; ct < 4; ++ct)
                acc[rt][ct] = __builtin_amdgcn_mfma_f32_16x16x32_bf16(
                    afr[rt], bfr[ct], acc[rt][ct], 0, 0, 0);
    }

    float a2v[4];
#pragma unroll
    for (int ct = 0; ct < 4; ++ct) a2v[ct] = a[F + wn * 64 + ct * 16 + l15];

    float ep[2][4];
#pragma unroll
    for (int rt = 0; rt < 2; ++rt)
#pragma unroll
        for (int g = 0; g < 4; ++g) {
            float s = 0.f;
#pragma unroll
            for (int ct = 0; ct < 4; ++ct) s += acc[rt][ct][g] * a2v[ct];
            ep[rt][g] = s;
        }
#pragma unroll
    for (int m = 1; m < 16; m <<= 1)
#pragma unroll
        for (int rt = 0; rt < 2; ++rt)
#pragma unroll
            for (int g = 0; g < 4; ++g)
                ep[rt][g] += __shfl_xor(ep[rt][g], m);

    if (l15 == 0)
#pragma unroll
        for (int rt = 0; rt < 2; ++rt)
#pragma unroll
            for (int g = 0; g < 4; ++g)
                epart[wn][wm * 32 + rt * 16 + quad * 4 + g] = ep[rt][g];
    __syncthreads();

#pragma unroll
    for (int rt = 0; rt < 2; ++rt)
#pragma unroll
        for (int ct = 0; ct < 4; ++ct) {
            const int o  = wn * 64 + ct * 16 + l15;
            const int r0 = wm * 32 + rt * 16 + quad * 4;
            const int n0 = nbase + r0;
            ushort4 v;
#pragma unroll
            for (int g = 0; g < 4; ++g) {
                const float e  = epart[0][r0 + g] + epart[1][r0 + g];
                const float pf = bf2f(bf16r(expf(e)));
                (&v.x)[g] = bf16r(pf * acc[rt][ct][g]);
            }
            size_t off = (size_t)batch * N * F + (size_t)(n0 >> 3) * 1024 + o * 8 + (n0 & 7);
            *(ushort4*)&Wb2[off] = v;
        }

    if (tid < 64) {
        const float e = epart[0][tid] + epart[1][tid];
        p16[batch * N + nbase + tid] = bf16r(expf(e));
    }
}

// K3 v8: ZERO machinery. No LDS, no barriers, no gll, no inline asm.
//   out[b][i][o] = (sum_j adj[b][i][j]*Wb2[j][o]) / (sum_j adj[b][i][j]*p[j])
// R4/R6/R8 evidence: k3 time is invariant to traffic (v7 with no adj ran the
// same ~65 us as v6 with 134 MB adj) -> the barrier/ring machinery itself is
// the cost (~4700 cyc/chunk). This version is the untried structure class:
// plain direct loads + pure TLP, with ALL in-loop operands L2-resident
// (Wb2 4 MB total, p16 32 KB, maskG 4 MB) and A synthesized from mask bits
// in VALU (exact 0.0/1.0 bf16 -> numerics identical to all prior rounds).
// Grid 512 = 2 blk/CU (b = blk&7 XCD pin), 4 waves/blk; wave = 32 rows x
// 32 cols (wid = col-slice), full j. Per K=32 chunk: 2 B b128 + 1 p b128
// (L2) + 40 VALU synth + 6 MFMA; 64 chunks. Compiler schedules freely;
// latency hidden by 8 waves/CU TLP + 4-chunk unrolled ILP per t-slot.
// Est: L2 B-traffic 268 MB ~ 7 us, VALU ~ 4 us, latency-bound floor ~10 us.
__global__ __launch_bounds__(256, 2) void k3_fused(const unsigned char* __restrict__ maskG,
                                                   const unsigned short* __restrict__ Wb2,
                                                   const unsigned short* __restrict__ p16,
                                                   float* __restrict__ out) {
    const int tid  = threadIdx.x;
    const int lane = tid & 63, wid = tid >> 6;      // wid = col-slice 0..3
    const int quad = lane >> 4, l15 = lane & 15;
    const int b  = blockIdx.x & 7;                  // XCD pin
    const int it = blockIdx.x >> 3;                 // 0..63
    const int i0 = it * 32;

    // Per-lane mask row pointers (row = i0 + rt*16 + l15; 256 B/row).
    const u32x4* mrow0 = (const u32x4*)(maskG + (size_t)(b * 2048 + i0 + l15) * 256);
    const u32x4* mrow1 = (const u32x4*)(maskG + (size_t)(b * 2048 + i0 + 16 + l15) * 256);
    // B image base for this batch; per-chunk fragment is contiguous b128.
    const char* wb = (const char*)Wb2 + (size_t)b * (N * F * 2)
                   + quad * 2048 + (wid * 32 + l15) * 16;
    // p base (lane addr depends on quad only -> broadcast loads).
    const char* pp = (const char*)p16 + (size_t)b * N * 2 + quad * 16;

    f32x4 acc[2][2] = {};
    f32x4 dacc[2] = {};

#pragma unroll 2
    for (int t = 0; t < 16; ++t) {
        const u32x4 q0 = mrow0[t];
        const u32x4 q1 = mrow1[t];
#pragma unroll
        for (int s = 0; s < 4; ++s) {
            const int j0 = t * 128 + s * 32;
            const char* bc = wb + (size_t)j0 * 256;
            bf16x8 bf0 = *(const bf16x8*)(bc);
            bf16x8 bf1 = *(const bf16x8*)(bc + 256);
            bf16x8 pv  = *(const bf16x8*)(pp + j0 * 2);

            // A-fragment synth from bits (v7-proven math): element e of af is
            // adj bit at j = j0 + quad*8 + e; even e -> uE bit base+e/2, odd e
            // -> uO bit base+(e-1)/2, base = (s&1)*16 + quad*4, u32 half = s>>1.
            const unsigned uE0 = (s >> 1) ? q0.y : q0.x;
            const unsigned uO0 = (s >> 1) ? q0.w : q0.z;
            const unsigned uE1 = (s >> 1) ? q1.y : q1.x;
            const unsigned uO1 = (s >> 1) ? q1.w : q1.z;
            const int base = (s & 1) * 16 + quad * 4;
            u32x4 aw0, aw1;
#pragma unroll
            for (int i = 0; i < 4; ++i) {
                const int bi = base + i;
                aw0[i] = (((uE0 >> bi) & 1u) ? 0x00003F80u : 0u)
                       | (((uO0 >> bi) & 1u) ? 0x3F800000u : 0u);
                aw1[i] = (((uE1 >> bi) & 1u) ? 0x00003F80u : 0u)
                       | (((uO1 >> bi) & 1u) ? 0x3F800000u : 0u);
            }
            bf16x8 af0 = __builtin_bit_cast(bf16x8, aw0);
            bf16x8 af1 = __builtin_bit_cast(bf16x8, aw1);

            acc[0][0] = __builtin_amdgcn_mfma_f32_16x16x32_bf16(af0, bf0, acc[0][0], 0, 0, 0);
            acc[0][1] = __builtin_amdgcn_mfma_f32_16x16x32_bf16(af0, bf1, acc[0][1], 0, 0, 0);
            acc[1][0] = __builtin_amdgcn_mfma_f32_16x16x32_bf16(af1, bf0, acc[1][0], 0, 0, 0);
            acc[1][1] = __builtin_amdgcn_mfma_f32_16x16x32_bf16(af1, bf1, acc[1][1], 0, 0, 0);
            dacc[0]   = __builtin_amdgcn_mfma_f32_16x16x32_bf16(af0, pv,  dacc[0],  0, 0, 0);
            dacc[1]   = __builtin_amdgcn_mfma_f32_16x16x32_bf16(af1, pv,  dacc[1],  0, 0, 0);
        }
    }

    // Epilogue: divide by per-row denominator (C/D row = quad*4+g holds the
    // matching dacc[rt][g] in every lane) and store final f32.
#pragma unroll
    for (int rt = 0; rt < 2; ++rt)
#pragma unroll
        for (int g = 0; g < 4; ++g) {
            const float inv = 1.0f / dacc[rt][g];
            float* orow = out + ((size_t)b * N + i0 + rt * 16 + quad * 4 + g) * F
                        + wid * 32 + l15;
            orow[0]  = acc[rt][0][g] * inv;
            orow[16] = acc[rt][1][g] * inv;
        }
}

// ---------------------------------------------------------------------------
extern "C" void kernel_launch(void* const* d_in, const int* in_sizes, int n_in,
                              void* d_out, int out_size, void* d_ws, size_t ws_size,
                              hipStream_t stream) {
    const float* h   = (const float*)d_in[0];
    const float* adj = (const float*)d_in[1];
    const float* W   = (const float*)d_in[2];
    const float* a   = (const float*)d_in[3];
    float* out = (float*)d_out;

    unsigned short* Wb2   = (unsigned short*)d_ws;                        // 4 MB
    unsigned short* p16   = (unsigned short*)((char*)d_ws + (4u << 20));  // 32 KB
    unsigned char*  maskG = (unsigned char*)((char*)d_ws + (8u << 20));   // 4 MB

    k01_wh<<<256 + 2048, 256, 0, stream>>>(h, adj, W, a, Wb2, p16, maskG);
    k3_fused<<<NB * 64, 256, 0, stream>>>(maskG, Wb2, p16, out);
}

// Round 10
// 239.915 us; speedup vs baseline: 1.0103x; 1.0027x over previous
//
#include <hip/hip_runtime.h>
#include <stdint.h>

#define AS1 __attribute__((address_space(1)))
#define AS3 __attribute__((address_space(3)))

typedef __bf16 bf16x8 __attribute__((ext_vector_type(8)));
typedef float f32x4 __attribute__((ext_vector_type(4)));
typedef unsigned int u32x4 __attribute__((ext_vector_type(4)));

constexpr int NB = 8;     // batches
constexpr int N  = 2048;  // nodes
constexpr int F  = 128;   // features (in == out)
constexpr size_t NSL = (size_t)NB * N * F;   // nump slice elements (bf16)
constexpr size_t DSL = (size_t)NB * N;       // denp slice elements (f32)

__device__ __forceinline__ unsigned short bf16r(float f) {
    unsigned u = __float_as_uint(f);
    return (unsigned short)((u + 0x7FFFu + ((u >> 16) & 1u)) >> 16);
}
__device__ __forceinline__ float bf2f(unsigned short s) {
    return __uint_as_float(((unsigned)s) << 16);
}

// ---------------------------------------------------------------------------
// Wb2 element layout (MFMA-B-operand native, linear in k-chunks):
//   byte(b, n, o) = b*N*F*2 + (n>>3)*2048 + o*16 + (n&7)*2
// K=32 chunk at j0 = contiguous 8192 B at b*N*F*2 + j0*256.
//
// maskG bit layout: per global row r (= b*2048+i), 256 B = 16 t-slots of
// 16 B; slot t covers j in [t*128,(t+1)*128) = {m0.lo,m0.hi,m1.lo,m1.hi},
// m0 bit l = adj bit at even j = t*128+2l, m1 = odd j.
// ---------------------------------------------------------------------------

// K01: fused k1 (blocks 0..255) + adj->bitmask compress (blocks 256..2303).
// [byte-identical to R8/R9's proven version]
__global__ __launch_bounds__(256) void k01_wh(const float* __restrict__ h,
                                              const float* __restrict__ adj,
                                              const float* __restrict__ W,
                                              const float* __restrict__ a,
                                              unsigned short* __restrict__ Wb2,
                                              unsigned short* __restrict__ p16,
                                              unsigned char* __restrict__ maskG) {
    const int tid  = threadIdx.x;
    const int lane = tid & 63, wid = tid >> 6;

    if (blockIdx.x >= 256) {
        const int cid = blockIdx.x - 256;           // 0..2047
#pragma unroll
        for (int rr = 0; rr < 2; ++rr) {
            const int row = cid * 8 + wid * 2 + rr;
            const float2* src = (const float2*)(adj + (size_t)row * 2048) + lane;
            u32x4* dst = (u32x4*)(maskG + (size_t)row * 256);
#pragma unroll 4
            for (int t = 0; t < 16; ++t) {
                float2 v = src[t * 64];
                unsigned long long m0 = __ballot(v.x > 0.5f);
                unsigned long long m1 = __ballot(v.y > 0.5f);
                if (lane == 0) {
                    u32x4 w = { (unsigned)m0, (unsigned)(m0 >> 32),
                                (unsigned)m1, (unsigned)(m1 >> 32) };
                    dst[t] = w;
                }
            }
        }
        return;
    }

    __shared__ float epart[2][64];

    const int quad = lane >> 4, l15 = lane & 15;
    const int wm = wid >> 1, wn = wid & 1;
    const int m0 = blockIdx.x * 64;
    const int batch = m0 >> 11;
    const int nbase = m0 & 2047;

    f32x4 acc[2][4] = {};

#pragma unroll
    for (int kk = 0; kk < 4; ++kk) {
        const int k = kk * 32 + quad * 8;
        bf16x8 afr[2], bfr[4];
#pragma unroll
        for (int rt = 0; rt < 2; ++rt) {
            const float* src = h + (size_t)(m0 + wm * 32 + rt * 16 + l15) * F + k;
            float4 x0 = *(const float4*)src;
            float4 x1 = *(const float4*)(src + 4);
            afr[rt][0] = (__bf16)x0.x; afr[rt][1] = (__bf16)x0.y;
            afr[rt][2] = (__bf16)x0.z; afr[rt][3] = (__bf16)x0.w;
            afr[rt][4] = (__bf16)x1.x; afr[rt][5] = (__bf16)x1.y;
            afr[rt][6] = (__bf16)x1.z; afr[rt][7] = (__bf16)x1.w;
        }
#pragma unroll
        for (int ct = 0; ct < 4; ++ct) {
            const int o = wn * 64 + ct * 16 + l15;
            const float* src = W + (size_t)o * F + k;
            float4 x0 = *(const float4*)src;
            float4 x1 = *(const float4*)(src + 4);
            bfr[ct][0] = (__bf16)x0.x; bfr[ct][1] = (__bf16)x0.y;
            bfr[ct][2] = (__bf16)x0.z; bfr[ct][3] = (__bf16)x0.w;
            bfr[ct][4] = (__bf16)x1.x; bfr[ct][5] = (__bf16)x1.y;
            bfr[ct][6] = (__bf16)x1.z; bfr[ct][7] = (__bf16)x1.w;
        }
#pragma unroll
        for (int rt = 0; rt < 2; ++rt)
#pragma unroll
            for (int ct = 0; ct < 4; ++ct)
                acc[rt][ct] = __builtin_amdgcn_mfma_f32_16x16x32_bf16(
                    afr[rt], bfr[ct], acc[rt][ct], 0, 0, 0);
    }

    float a2v[4];
#pragma unroll
    for (int ct = 0; ct < 4; ++ct) a2v[ct] = a[F + wn * 64 + ct * 16 + l15];

    float ep[2][4];
#pragma unroll
    for (int rt = 0; rt < 2; ++rt)
#pragma unroll
        for (int g = 0; g < 4; ++g) {
            float s = 0.f;
#pragma unroll
            for (int ct = 0; ct < 4; ++ct) s += acc[rt][ct][g] * a2v[ct];
            ep[rt][g] = s;
        }
#pragma unroll
    for (int m = 1; m < 16; m <<= 1)
#pragma unroll
        for (int rt = 0; rt < 2; ++rt)
#pragma unroll
            for (int g = 0; g < 4; ++g)
                ep[rt][g] += __shfl_xor(ep[rt][g], m);

    if (l15 == 0)
#pragma unroll
        for (int rt = 0; rt < 2; ++rt)
#pragma unroll
            for (int g = 0; g < 4; ++g)
                epart[wn][wm * 32 + rt * 16 + quad * 4 + g] = ep[rt][g];
    __syncthreads();

#pragma unroll
    for (int rt = 0; rt < 2; ++rt)
#pragma unroll
        for (int ct = 0; ct < 4; ++ct) {
            const int o  = wn * 64 + ct * 16 + l15;
            const int r0 = wm * 32 + rt * 16 + quad * 4;
            const int n0 = nbase + r0;
            ushort4 v;
#pragma unroll
            for (int g = 0; g < 4; ++g) {
                const float e  = epart[0][r0 + g] + epart[1][r0 + g];
                const float pf = bf2f(bf16r(expf(e)));
                (&v.x)[g] = bf16r(pf * acc[rt][ct][g]);
            }
            size_t off = (size_t)batch * N * F + (size_t)(n0 >> 3) * 1024 + o * 8 + (n0 & 7);
            *(ushort4*)&Wb2[off] = v;
        }

    if (tid < 64) {
        const float e = epart[0][tid] + epart[1][tid];
        p16[batch * N + nbase + tid] = bf16r(expf(e));
    }
}

// K3 v9: MINIMIZE PER-CU BYTES (the one lever that has ever worked).
// Model from R2-R9: delivered VMEM pins at ~8-11 B/cyc/CU regardless of
// source tier (L1-miss refill path). B-read total = 8192/BM MB -> BM=256
// cuts it to 33.5 MB; j-split x8 keeps grid 512 (2 blk/CU). Per-CU in-loop
// bytes ~145 KB -> ~7 us. Partial num/denom per j-eighth; k4 reduces+divides.
//   nump[jq][b][i][o] = sum_{j in q} adjbit*Wb2[j][o]  (bf16, R0-proven)
//   denp[jq][b][i]    = sum_{j in q} adjbit*p[j]       (f32)
// Block = (b, 256-row it, 256-wide jq): 512 thr = 8 waves (4 row x 2 col),
// wave = 64 rows x 64 cols. A synthesized from 8 KB LDS bitmask (exact
// 0/1 bf16, v8-proven mapping). B via v6's proven gll ring-3 + counted
// vmcnt(2) + raw double barrier; 1 gll/wave/chunk; 8 chunks of K=32.
// LDS: B 3x8 KB + mask 8 KB (u32x4[2][256]: 16 B row-stride -> 2-way free)
// + p 512 B = 33 KB. b = blk&7 XCD pin.
__global__ __launch_bounds__(512, 2) void k3_attn(const unsigned char* __restrict__ maskG,
                                                  const unsigned short* __restrict__ Wb2,
                                                  const unsigned short* __restrict__ p16,
                                                  unsigned short* __restrict__ nump,
                                                  float* __restrict__ denp) {
    __shared__ __align__(16) char  Bsm_[3][8192];
    __shared__ __align__(16) u32x4 Msm_[2][256];
    __shared__ __align__(16) char  Psm_[512];

    const int tid  = threadIdx.x;
    const int lane = tid & 63, wid = tid >> 6;      // 8 waves
    const int quad = lane >> 4, l15 = lane & 15;
    const int wr = wid >> 1, wn = wid & 1;          // 4 row-groups x 2 col-halves
    const int b  = blockIdx.x & 7;                  // XCD pin
    const int r  = blockIdx.x >> 3;                 // 0..63
    const int it = r >> 3, jq = r & 7;
    const int i0 = it * 256;

    // --- prologue staging (all drained by one syncthreads) ---
    // mask: 8 KB; thread t -> row t>>1, slot-parity t&1 (slots 2jq, 2jq+1).
    const int mr = tid >> 1, ms = tid & 1;
    u32x4 mv = *(const u32x4*)(maskG + (size_t)(b * 2048 + i0 + mr) * 256
                               + (size_t)(2 * jq + ms) * 16);
    // p: 512 B (this jq's slice), threads 0..31.
    u32x4 pvv = {};
    if (tid < 32)
        pvv = *(const u32x4*)((const char*)p16 + (size_t)b * N * 2 + jq * 512 + tid * 16);
    Msm_[ms][mr] = mv;
    if (tid < 32) *(u32x4*)&Psm_[tid * 16] = pvv;

    // B gll source: chunk = 8 KB; wave stages 1 KB at wid*1024.
    const char* bSrc = (const char*)Wb2 + (size_t)b * (N * F * 2)
                     + (size_t)jq * 65536 + wid * 1024 + lane * 16;

#define K3_STAGE(BI, C)                                                            \
    __builtin_amdgcn_global_load_lds(                                              \
        (const AS1 void*)(bSrc + (size_t)(C) * 8192),                              \
        (AS3 void*)(&Bsm_[BI][wid * 1024]), 16, 0, 0);

    f32x4 acc[4][4] = {};
    f32x4 dacc[4] = {};

    K3_STAGE(0, 0)
    K3_STAGE(1, 1)
    K3_STAGE(2, 2)
    __syncthreads();   // one-time full drain: mask + p + chunks 0-2

#define K3_CHUNK(C, BI, WAITSTR, DOSTAGE)                                          \
    {                                                                              \
        asm volatile(WAITSTR ::: "memory");                                        \
        __builtin_amdgcn_s_barrier();                                              \
        __builtin_amdgcn_sched_barrier(0);                                         \
        const char* bB = &Bsm_[BI][0];                                             \
        bf16x8 pv = *(const bf16x8*)(&Psm_[(C) * 64 + quad * 16]);                 \
        bf16x8 bfv[4];                                                             \
        _Pragma("unroll")                                                          \
        for (int ct = 0; ct < 4; ++ct)                                             \
            bfv[ct] = *(const bf16x8*)(bB + quad * 2048                            \
                          + (wn * 64 + ct * 16 + l15) * 16);                       \
        _Pragma("unroll")                                                          \
        for (int rt = 0; rt < 4; ++rt) {                                           \
            const int row = wr * 64 + rt * 16 + l15;                               \
            u32x4 q = Msm_[(C) >> 2][row];                                         \
            const unsigned uE = ((C) & 2) ? q.y : q.x;                             \
            const unsigned uO = ((C) & 2) ? q.w : q.z;                             \
            const int base = ((C) & 1) * 16 + quad * 4;                            \
            u32x4 aw;                                                              \
            _Pragma("unroll")                                                      \
            for (int i = 0; i < 4; ++i) {                                          \
                const int bi_ = base + i;                                          \
                aw[i] = (((uE >> bi_) & 1u) ? 0x00003F80u : 0u)                    \
                      | (((uO >> bi_) & 1u) ? 0x3F800000u : 0u);                   \
            }                                                                      \
            bf16x8 af = __builtin_bit_cast(bf16x8, aw);                            \
            _Pragma("unroll")                                                      \
            for (int ct = 0; ct < 4; ++ct)                                         \
                acc[rt][ct] = __builtin_amdgcn_mfma_f32_16x16x32_bf16(             \
                    af, bfv[ct], acc[rt][ct], 0, 0, 0);                            \
            dacc[rt] = __builtin_amdgcn_mfma_f32_16x16x32_bf16(                    \
                af, pv, dacc[rt], 0, 0, 0);                                        \
        }                                                                          \
        if (DOSTAGE) {                                                             \
            __builtin_amdgcn_s_barrier();                                          \
            __builtin_amdgcn_sched_barrier(0);                                     \
            K3_STAGE(BI, (C) + 3)                                                  \
        }                                                                          \
    }

    // 8 chunks of K=32 (j-range jq*256..+256). Steady wait vmcnt(2)
    // (own gll: 1/chunk, 2 newer in flight); never 0 mid-loop.
    K3_CHUNK(0, 0, "s_waitcnt vmcnt(2)", 1)
    K3_CHUNK(1, 1, "s_waitcnt vmcnt(2)", 1)
    K3_CHUNK(2, 2, "s_waitcnt vmcnt(2)", 1)
    K3_CHUNK(3, 0, "s_waitcnt vmcnt(2)", 1)
    K3_CHUNK(4, 1, "s_waitcnt vmcnt(2)", 1)
    K3_CHUNK(5, 2, "s_waitcnt vmcnt(2)", 0)
    K3_CHUNK(6, 0, "s_waitcnt vmcnt(1)", 0)
    K3_CHUNK(7, 1, "s_waitcnt vmcnt(0)", 0)

#undef K3_CHUNK
#undef K3_STAGE

    // Partial writes (bf16 numerators, f32 denominators; no division here).
    unsigned short* np = nump + (size_t)jq * NSL + (size_t)b * N * F;
    float* dp = denp + (size_t)jq * DSL + (size_t)b * N;
#pragma unroll
    for (int rt = 0; rt < 4; ++rt) {
#pragma unroll
        for (int ct = 0; ct < 4; ++ct) {
            const int o = wn * 64 + ct * 16 + l15;
#pragma unroll
            for (int g = 0; g < 4; ++g) {
                const int i = i0 + wr * 64 + rt * 16 + quad * 4 + g;
                np[(size_t)i * F + o] = bf16r(acc[rt][ct][g]);
            }
        }
        if (l15 == 0)
#pragma unroll
            for (int g = 0; g < 4; ++g)
                dp[i0 + wr * 64 + rt * 16 + quad * 4 + g] = dacc[rt][g];
    }
}

// K4: out[b][i][o] = (sum_q nump[q][b][i][o]) / (sum_q denp[q][b][i])
// 2048 blocks (b = blk&7), 8 rows/block, 4 o's/thread. ~40 MB stream.
__global__ __launch_bounds__(256) void k4_reduce(const unsigned short* __restrict__ nump,
                                                 const float* __restrict__ denp,
                                                 float* __restrict__ out) {
    const int b   = blockIdx.x & 7;
    const int row = (blockIdx.x >> 3) * 8 + (threadIdx.x >> 5);
    const int o4  = (threadIdx.x & 31) * 4;
    const size_t base = ((size_t)b * N + row) * F + o4;

    float s0 = 0.f, s1 = 0.f, s2 = 0.f, s3 = 0.f, d = 0.f;
#pragma unroll
    for (int q = 0; q < 8; ++q) {
        ushort4 v = *(const ushort4*)&nump[q * NSL + base];
        s0 += bf2f(v.x); s1 += bf2f(v.y); s2 += bf2f(v.z); s3 += bf2f(v.w);
        d  += denp[q * DSL + (size_t)b * N + row];
    }
    const float inv = 1.0f / d;
    f32x4 o = { s0 * inv, s1 * inv, s2 * inv, s3 * inv };
    *(f32x4*)&out[base] = o;
}

// ---------------------------------------------------------------------------
extern "C" void kernel_launch(void* const* d_in, const int* in_sizes, int n_in,
                              void* d_out, int out_size, void* d_ws, size_t ws_size,
                              hipStream_t stream) {
    const float* h   = (const float*)d_in[0];
    const float* adj = (const float*)d_in[1];
    const float* W   = (const float*)d_in[2];
    const float* a   = (const float*)d_in[3];
    float* out = (float*)d_out;

    unsigned short* Wb2   = (unsigned short*)d_ws;                        // 4 MB
    unsigned short* p16   = (unsigned short*)((char*)d_ws + (4u << 20));  // 32 KB
    unsigned char*  maskG = (unsigned char*)((char*)d_ws + (8u << 20));   // 4 MB
    unsigned short* nump  = (unsigned short*)((char*)d_ws + (16u << 20)); // 32 MB
    float*          denp  = (float*)((char*)d_ws + (48u << 20));          // 512 KB

    k01_wh<<<256 + 2048, 256, 0, stream>>>(h, adj, W, a, Wb2, p16, maskG);
    k3_attn<<<NB * 64, 512, 0, stream>>>(maskG, Wb2, p16, nump, denp);
    k4_reduce<<<NB * N / 8, 256, 0, stream>>>(nump, denp, out);
}

// Round 11
// 219.762 us; speedup vs baseline: 1.1030x; 1.0917x over previous
//
#include <hip/hip_runtime.h>
#include <stdint.h>

#define AS1 __attribute__((address_space(1)))
#define AS3 __attribute__((address_space(3)))

typedef __bf16 bf16x8 __attribute__((ext_vector_type(8)));
typedef float f32x4 __attribute__((ext_vector_type(4)));

constexpr int NB = 8;     // batches
constexpr int N  = 2048;  // nodes
constexpr int F  = 128;   // features (in == out)

__device__ __forceinline__ unsigned short bf16r(float f) {
    unsigned u = __float_as_uint(f);
    return (unsigned short)((u + 0x7FFFu + ((u >> 16) & 1u)) >> 16);
}
__device__ __forceinline__ float bf2f(unsigned short s) {
    return __uint_as_float(((unsigned)s) << 16);
}

// ---------------------------------------------------------------------------
// Wb2 element layout (MFMA-B-operand native, linear in k-chunks):
//   byte(b, n, o) = b*N*F*2 + (n>>3)*2048 + o*16 + (n&7)*2
// BK=64 chunk c = contiguous 16384 B at b*N*F*2 + c*16384.
// ---------------------------------------------------------------------------

// K1 (fused): Wh = h @ W^T;  e = Wh @ a2;  p = exp(e);
//   p16 = bf16(p);  Wb2 = bf16(bf2f(p16) * Wh)        [unchanged, proven]
__global__ __launch_bounds__(256) void k1_wh(const float* __restrict__ h,
                                             const float* __restrict__ W,
                                             const float* __restrict__ a,
                                             unsigned short* __restrict__ Wb2,
                                             unsigned short* __restrict__ p16) {
    __shared__ float epart[2][64];

    const int tid  = threadIdx.x;
    const int lane = tid & 63, wid = tid >> 6;
    const int quad = lane >> 4, l15 = lane & 15;
    const int wm = wid >> 1, wn = wid & 1;
    const int m0 = blockIdx.x * 64;
    const int batch = m0 >> 11;
    const int nbase = m0 & 2047;

    f32x4 acc[2][4] = {};

#pragma unroll
    for (int kk = 0; kk < 4; ++kk) {
        const int k = kk * 32 + quad * 8;
        bf16x8 afr[2], bfr[4];
#pragma unroll
        for (int rt = 0; rt < 2; ++rt) {
            const float* src = h + (size_t)(m0 + wm * 32 + rt * 16 + l15) * F + k;
            float4 x0 = *(const float4*)src;
            float4 x1 = *(const float4*)(src + 4);
            afr[rt][0] = (__bf16)x0.x; afr[rt][1] = (__bf16)x0.y;
            afr[rt][2] = (__bf16)x0.z; afr[rt][3] = (__bf16)x0.w;
            afr[rt][4] = (__bf16)x1.x; afr[rt][5] = (__bf16)x1.y;
            afr[rt][6] = (__bf16)x1.z; afr[rt][7] = (__bf16)x1.w;
        }
#pragma unroll
        for (int ct = 0; ct < 4; ++ct) {
            const int o = wn * 64 + ct * 16 + l15;
            const float* src = W + (size_t)o * F + k;
            float4 x0 = *(const float4*)src;
            float4 x1 = *(const float4*)(src + 4);
            bfr[ct][0] = (__bf16)x0.x; bfr[ct][1] = (__bf16)x0.y;
            bfr[ct][2] = (__bf16)x0.z; bfr[ct][3] = (__bf16)x0.w;
            bfr[ct][4] = (__bf16)x1.x; bfr[ct][5] = (__bf16)x1.y;
            bfr[ct][6] = (__bf16)x1.z; bfr[ct][7] = (__bf16)x1.w;
        }
#pragma unroll
        for (int rt = 0; rt < 2; ++rt)
#pragma unroll
            for (int ct = 0; ct < 4; ++ct)
                acc[rt][ct] = __builtin_amdgcn_mfma_f32_16x16x32_bf16(
                    afr[rt], bfr[ct], acc[rt][ct], 0, 0, 0);
    }

    float a2v[4];
#pragma unroll
    for (int ct = 0; ct < 4; ++ct) a2v[ct] = a[F + wn * 64 + ct * 16 + l15];

    float ep[2][4];
#pragma unroll
    for (int rt = 0; rt < 2; ++rt)
#pragma unroll
        for (int g = 0; g < 4; ++g) {
            float s = 0.f;
#pragma unroll
            for (int ct = 0; ct < 4; ++ct) s += acc[rt][ct][g] * a2v[ct];
            ep[rt][g] = s;
        }
#pragma unroll
    for (int m = 1; m < 16; m <<= 1)
#pragma unroll
        for (int rt = 0; rt < 2; ++rt)
#pragma unroll
            for (int g = 0; g < 4; ++g)
                ep[rt][g] += __shfl_xor(ep[rt][g], m);

    if (l15 == 0)
#pragma unroll
        for (int rt = 0; rt < 2; ++rt)
#pragma unroll
            for (int g = 0; g < 4; ++g)
                epart[wn][wm * 32 + rt * 16 + quad * 4 + g] = ep[rt][g];
    __syncthreads();

#pragma unroll
    for (int rt = 0; rt < 2; ++rt)
#pragma unroll
        for (int ct = 0; ct < 4; ++ct) {
            const int o  = wn * 64 + ct * 16 + l15;
            const int r0 = wm * 32 + rt * 16 + quad * 4;
            const int n0 = nbase + r0;
            ushort4 v;
#pragma unroll
            for (int g = 0; g < 4; ++g) {
                const float e  = epart[0][r0 + g] + epart[1][r0 + g];
                const float pf = bf2f(bf16r(expf(e)));
                (&v.x)[g] = bf16r(pf * acc[rt][ct][g]);
            }
            size_t off = (size_t)batch * N * F + (size_t)(n0 >> 3) * 1024 + o * 8 + (n0 & 7);
            *(ushort4*)&Wb2[off] = v;
        }

    if (tid < 64) {
        const float e = epart[0][tid] + epart[1][tid];
        p16[batch * N + nbase + tid] = bf16r(expf(e));
    }
}

// K3 v10: R7's session-best v6 (217.5 us total) with ONE controlled delta:
// ring 3 -> 2 (LDS 100 KB -> 68 KB) so 2 BLOCKS/CU fit. v6 at 1 blk/CU made
// every barrier a whole-CU stall (no cross-block overlap, m114 mechanism
// idle); with 2 independent blocks per CU, one block's MFMA/ds_read phase
// covers the other's stage/vmcnt phase. Bytes, addressing, swizzles, and
// the m201 counted-vmcnt template are byte-identical to R7.
//   out[b][i][o] = (sum_j adj[b][i][j]*Wb2[j][o]) / (sum_j adj[b][i][j]*p[j])
// BM=64 rows/block, grid 256 (blk&7 = batch XCD pin), 512 thr = 8 waves
// (2Mx4N). BK=64, 32 chunks, ring-2 shared buffers (compile-time indices),
// 4 gll/wave/chunk (2 A + 2 B), own-loads counted vmcnt(4) BEFORE raw
// s_barrier (never 0 mid-loop), second barrier before restage (WAR-safe).
// A XOR-swizzled 16B granules (slot g of row r holds granule g^(r&15) ->
// all LDS reads <=2-way bank = free); B staged linear (MFMA-native image).
// Denominator via MFMA vs p16; divide in-register; final f32 out.
__global__ __launch_bounds__(512, 2) void k3_fused(const float* __restrict__ adj,
                                                   const unsigned short* __restrict__ Wb2,
                                                   const unsigned short* __restrict__ p16,
                                                   float* __restrict__ out) {
    __shared__ __align__(16) char Asm_[2][16384];   // 64 rows x 64 k f32, swizzled
    __shared__ __align__(16) char Bsm_[2][16384];   // 64 k x 128 o bf16, linear image
    __shared__ __align__(16) char Psm_[4096];       // 2048 x bf16

    const int tid  = threadIdx.x;
    const int lane = tid & 63, wid = tid >> 6;      // 8 waves
    const int quad = lane >> 4, l15 = lane & 15;
    const int wr = wid >> 2, wc = wid & 3;          // row-half / col-quarter
    const int b  = blockIdx.x & 7;
    const int it = blockIdx.x >> 3;                 // 0..31
    const int i0 = it * 64;

    // A stage sources (2 gll/wave/chunk): instr ii = wid*2+s covers rows
    // ii*4+(lane>>4); granule slot (lane&15) receives granule (lane&15)^(r&15).
    const float* aSrc[2];
#pragma unroll
    for (int s = 0; s < 2; ++s) {
        const int rl = (wid * 2 + s) * 4 + (lane >> 4);
        const int G  = (lane & 15) ^ (rl & 15);
        aSrc[s] = adj + (size_t)b * N * N + (size_t)(i0 + rl) * N + G * 4;
    }
    // B stage source (2 gll/wave/chunk): linear 16 KB chunk image, wave's 2 KB.
    const char* bSrc = (const char*)Wb2 + (size_t)b * (N * F * 2)
                     + wid * 2048 + lane * 16;
    // p16 source (4 KB once, wave 0).
    const char* pSrc = (const char*)p16 + (size_t)b * N * 2 + lane * 16;

#define K3_STAGE(BI, C)                                                            \
    do {                                                                           \
        __builtin_amdgcn_global_load_lds((const AS1 void*)(aSrc[0] + (C) * 64),    \
            (AS3 void*)(&Asm_[BI][(wid * 2 + 0) * 1024]), 16, 0, 0);               \
        __builtin_amdgcn_global_load_lds((const AS1 void*)(aSrc[1] + (C) * 64),    \
            (AS3 void*)(&Asm_[BI][(wid * 2 + 1) * 1024]), 16, 0, 0);               \
        __builtin_amdgcn_global_load_lds(                                          \
            (const AS1 void*)(bSrc + (size_t)(C) * 16384 + 0 * 1024),              \
            (AS3 void*)(&Bsm_[BI][wid * 2048 + 0 * 1024]), 16, 0, 0);              \
        __builtin_amdgcn_global_load_lds(                                          \
            (const AS1 void*)(bSrc + (size_t)(C) * 16384 + 1 * 1024),              \
            (AS3 void*)(&Bsm_[BI][wid * 2048 + 1 * 1024]), 16, 0, 0);              \
    } while (0)

    f32x4 acc[2][2] = {};
    f32x4 dacc[2] = {};

    // Prologue: p (wave 0; oldest in its queue, drained by chunk-0's vmcnt(4)),
    // then fill the 2-deep ring (8 gll/wave in flight).
    if (wid == 0) {
#pragma unroll
        for (int s = 0; s < 4; ++s)
            __builtin_amdgcn_global_load_lds((const AS1 void*)(pSrc + s * 1024),
                (AS3 void*)(&Psm_[s * 1024]), 16, 0, 0);
    }
    K3_STAGE(0, 0);
    K3_STAGE(1, 1);

#define K3_CHUNK(C, BI, WAITSTR, DOSTAGE)                                          \
    {                                                                              \
        asm volatile(WAITSTR ::: "memory");                                        \
        __builtin_amdgcn_s_barrier();                                              \
        __builtin_amdgcn_sched_barrier(0);                                         \
        const char* aB = &Asm_[BI][0];                                             \
        const char* bB = &Bsm_[BI][0];                                             \
        _Pragma("unroll")                                                          \
        for (int ks = 0; ks < 2; ++ks) {                                           \
            bf16x8 pv = *(const bf16x8*)(&Psm_[(C) * 128 + ks * 64 + quad * 16]);  \
            bf16x8 af[2];                                                          \
            _Pragma("unroll")                                                      \
            for (int rt = 0; rt < 2; ++rt) {                                       \
                const int row = wr * 32 + rt * 16 + l15;                           \
                const int G0  = ks * 8 + quad * 2;                                 \
                f32x4 x0 = *(const f32x4*)(aB + row * 256                          \
                              + (((G0 + 0) ^ (row & 15)) << 4));                   \
                f32x4 x1 = *(const f32x4*)(aB + row * 256                          \
                              + (((G0 + 1) ^ (row & 15)) << 4));                   \
                af[rt][0] = (__bf16)x0[0]; af[rt][1] = (__bf16)x0[1];              \
                af[rt][2] = (__bf16)x0[2]; af[rt][3] = (__bf16)x0[3];              \
                af[rt][4] = (__bf16)x1[0]; af[rt][5] = (__bf16)x1[1];              \
                af[rt][6] = (__bf16)x1[2]; af[rt][7] = (__bf16)x1[3];              \
            }                                                                      \
            _Pragma("unroll")                                                      \
            for (int ct = 0; ct < 2; ++ct) {                                       \
                bf16x8 bf = *(const bf16x8*)(bB + (ks * 4 + quad) * 2048           \
                                + (wc * 32 + ct * 16) * 16 + l15 * 16);            \
                acc[0][ct] = __builtin_amdgcn_mfma_f32_16x16x32_bf16(              \
                    af[0], bf, acc[0][ct], 0, 0, 0);                               \
                acc[1][ct] = __builtin_amdgcn_mfma_f32_16x16x32_bf16(              \
                    af[1], bf, acc[1][ct], 0, 0, 0);                               \
            }                                                                      \
            dacc[0] = __builtin_amdgcn_mfma_f32_16x16x32_bf16(                     \
                af[0], pv, dacc[0], 0, 0, 0);                                      \
            dacc[1] = __builtin_amdgcn_mfma_f32_16x16x32_bf16(                     \
                af[1], pv, dacc[1], 0, 0, 0);                                      \
        }                                                                          \
        if (DOSTAGE) {                                                             \
            __builtin_amdgcn_s_barrier();                                          \
            __builtin_amdgcn_sched_barrier(0);                                     \
            K3_STAGE(BI, (C) + 2);                                                 \
        }                                                                          \
    }

    // Main: chunk c restages c+2 (c <= 29; last staged = 31). Ring index is
    // compile-time everywhere; steady-state wait = vmcnt(4) (= 1 newer chunk
    // x 4 own loads in flight); never drains to 0 mid-loop.
    for (int c2 = 0; c2 < 30; c2 += 2) {
        K3_CHUNK(c2 + 0, 0, "s_waitcnt vmcnt(4)", 1)
        K3_CHUNK(c2 + 1, 1, "s_waitcnt vmcnt(4)", 1)
    }
    K3_CHUNK(30, 0, "s_waitcnt vmcnt(4)", 0)
    K3_CHUNK(31, 1, "s_waitcnt vmcnt(0)", 0)

#undef K3_CHUNK
#undef K3_STAGE

    // Epilogue: divide by per-row denominator (C/D row = quad*4+g holds the
    // matching dacc[rt][g] in every lane) and store final f32.
#pragma unroll
    for (int rt = 0; rt < 2; ++rt)
#pragma unroll
        for (int g = 0; g < 4; ++g) {
            const float inv = 1.0f / dacc[rt][g];
            float* orow = out + ((size_t)b * N + i0 + wr * 32 + rt * 16
                                 + quad * 4 + g) * F + wc * 32 + l15;
            orow[0]  = acc[rt][0][g] * inv;
            orow[16] = acc[rt][1][g] * inv;
        }
}

// ---------------------------------------------------------------------------
extern "C" void kernel_launch(void* const* d_in, const int* in_sizes, int n_in,
                              void* d_out, int out_size, void* d_ws, size_t ws_size,
                              hipStream_t stream) {
    const float* h   = (const float*)d_in[0];
    const float* adj = (const float*)d_in[1];
    const float* W   = (const float*)d_in[2];
    const float* a   = (const float*)d_in[3];
    float* out = (float*)d_out;

    unsigned short* Wb2 = (unsigned short*)d_ws;                        // 4 MB
    unsigned short* p16 = (unsigned short*)((char*)d_ws + (4u << 20));  // 32 KB

    k1_wh<<<NB * N / 64, 256, 0, stream>>>(h, W, a, Wb2, p16);
    k3_fused<<<NB * 32, 512, 0, stream>>>(adj, Wb2, p16, out);
}